// Round 1
// baseline (45.885 us; speedup 1.0000x reference)
//
#include <hip/hip_runtime.h>
#include <hip/hip_bf16.h>

typedef __bf16 bf16_t;
typedef __bf16 bf16x4 __attribute__((ext_vector_type(4)));
typedef __bf16 bf16x8 __attribute__((ext_vector_type(8)));
typedef float  f32x4  __attribute__((ext_vector_type(4)));

static constexpr int Mtot = 4096;   // B*S
static constexpr int Ntot = 1024;   // H*A
static constexpr int Ktot = 1024;   // F
static constexpr int BM = 128, BN = 128, BK = 32;
static constexpr int BKP = 40;      // padded LDS K-stride (bf16): 80 B rows, 16B-aligned, bank-friendly

// out[b,s,h,a] = sum_f value_input[b,s,f] * v_w[h,f,a]
// (softmax over q in the reference integrates to 1 in the final q-contraction,
//  so the whole op reduces to the value projection GEMM)
// A = value_input as [M=4096][K=1024] row-major fp32
// B = v_w as (k,n) -> W[(n>>6)*65536 + k*64 + (n&63)]  (n = h*64+a)
// C = out as [M][N=1024] row-major fp32
__global__ __launch_bounds__(256, 1)
void vproj_gemm_kernel(const float* __restrict__ A,
                       const float* __restrict__ W,
                       float* __restrict__ C)
{
    __shared__ bf16_t As[BM][BKP];
    __shared__ bf16_t Bs[BN][BKP];   // B stored transposed: [n][k]

    const int t    = threadIdx.x;
    const int lane = t & 63;
    const int wave = t >> 6;   // 0..3
    const int wm   = wave >> 1;
    const int wn   = wave & 1;

    const int bm = blockIdx.y * BM;
    const int bn = blockIdx.x * BN;

    // B staging: per thread, 4 consecutive cols (n) x 4 consecutive k-rows
    const int nb0 = (t & 31) << 2;   // 0..124
    const int rb0 = (t >> 5) << 2;   // 0..28

    f32x4 acc[4][4];
#pragma unroll
    for (int i = 0; i < 4; ++i)
#pragma unroll
        for (int j = 0; j < 4; ++j) {
            f32x4 z = {0.f, 0.f, 0.f, 0.f};
            acc[i][j] = z;
        }

    const int lrow = lane & 15;          // fragment row (A) / col (B)
    const int lk   = (lane >> 4) << 3;   // k-offset: 8 contiguous per lane-group

    for (int k0 = 0; k0 < Ktot; k0 += BK) {
        __syncthreads();   // previous iteration's reads done before overwrite

        // ---- stage A: [BM][BK] fp32 -> bf16 row-major; fully coalesced float4 ----
#pragma unroll
        for (int r = 0; r < 4; ++r) {
            const int idx  = r * 256 + t;       // 0..1023 float4-slots
            const int arow = idx >> 3;          // 0..127
            const int acol = (idx & 7) << 2;    // 0,4,...,28
            const float4 v = *(const float4*)(A + (size_t)(bm + arow) * Ktot + (k0 + acol));
            bf16x4 p = {(bf16_t)v.x, (bf16_t)v.y, (bf16_t)v.z, (bf16_t)v.w};
            *(bf16x4*)&As[arow][acol] = p;
        }

        // ---- stage B: global [BK][BN] -> LDS transposed [BN][BK], 4x4 micro-tiles ----
        {
            const int gn = bn + nb0;
            const float* wp = W + (((size_t)(gn >> 6)) << 16)
                                + (size_t)(k0 + rb0) * 64 + (gn & 63);
            const float4 r0 = *(const float4*)(wp);
            const float4 r1 = *(const float4*)(wp + 64);
            const float4 r2 = *(const float4*)(wp + 128);
            const float4 r3 = *(const float4*)(wp + 192);
            bf16x4 c0 = {(bf16_t)r0.x, (bf16_t)r1.x, (bf16_t)r2.x, (bf16_t)r3.x};
            bf16x4 c1 = {(bf16_t)r0.y, (bf16_t)r1.y, (bf16_t)r2.y, (bf16_t)r3.y};
            bf16x4 c2 = {(bf16_t)r0.z, (bf16_t)r1.z, (bf16_t)r2.z, (bf16_t)r3.z};
            bf16x4 c3 = {(bf16_t)r0.w, (bf16_t)r1.w, (bf16_t)r2.w, (bf16_t)r3.w};
            *(bf16x4*)&Bs[nb0 + 0][rb0] = c0;
            *(bf16x4*)&Bs[nb0 + 1][rb0] = c1;
            *(bf16x4*)&Bs[nb0 + 2][rb0] = c2;
            *(bf16x4*)&Bs[nb0 + 3][rb0] = c3;
        }
        __syncthreads();

        // ---- fragments + MFMA ----
        bf16x8 afr[4], bfr[4];
#pragma unroll
        for (int mf = 0; mf < 4; ++mf)
            afr[mf] = *(const bf16x8*)&As[wm * 64 + mf * 16 + lrow][lk];
#pragma unroll
        for (int nf = 0; nf < 4; ++nf)
            bfr[nf] = *(const bf16x8*)&Bs[wn * 64 + nf * 16 + lrow][lk];
#pragma unroll
        for (int mf = 0; mf < 4; ++mf)
#pragma unroll
            for (int nf = 0; nf < 4; ++nf)
                acc[mf][nf] = __builtin_amdgcn_mfma_f32_16x16x32_bf16(
                    afr[mf], bfr[nf], acc[mf][nf], 0, 0, 0);
    }

    // ---- epilogue: verified C/D layout col = lane&15, row = (lane>>4)*4 + i ----
#pragma unroll
    for (int mf = 0; mf < 4; ++mf) {
        const int row0 = bm + wm * 64 + mf * 16 + ((lane >> 4) << 2);
#pragma unroll
        for (int nf = 0; nf < 4; ++nf) {
            const int col = bn + wn * 64 + nf * 16 + (lane & 15);
#pragma unroll
            for (int i = 0; i < 4; ++i)
                C[(size_t)(row0 + i) * Ntot + col] = acc[mf][nf][i];
        }
    }
}

extern "C" void kernel_launch(void* const* d_in, const int* in_sizes, int n_in,
                              void* d_out, int out_size, void* d_ws, size_t ws_size,
                              hipStream_t stream) {
    (void)in_sizes; (void)n_in; (void)d_ws; (void)ws_size; (void)out_size;
    // setup_inputs order: key_input, query_input, value_input, q_w, k_w, v_w
    const float* V  = (const float*)d_in[2];   // [B,S,F] = [M][K]
    const float* Vw = (const float*)d_in[5];   // [H,F,A]
    float* out      = (float*)d_out;           // [B,S,H,A] = [M][N]

    dim3 grid(Ntot / BN, Mtot / BM);           // (8, 32) = 256 workgroups
    hipLaunchKernelGGL(vproj_gemm_kernel, grid, dim3(256), 0, stream, V, Vw, out);
}

// Round 2
// 33.167 us; speedup vs baseline: 1.3834x; 1.3834x over previous
//
#include <hip/hip_runtime.h>
#include <hip/hip_bf16.h>

typedef __bf16 bf16_t;
typedef __bf16 bf16x4 __attribute__((ext_vector_type(4)));
typedef __bf16 bf16x8 __attribute__((ext_vector_type(8)));
typedef float  f32x4  __attribute__((ext_vector_type(4)));

static constexpr int Mtot = 4096;   // B*S
static constexpr int Ntot = 1024;   // H*A
static constexpr int Ktot = 1024;   // F
static constexpr int BM = 128, BN = 128, BK = 64;
static constexpr int BKP = 72;      // LDS row stride in bf16 (144 B, 16B-aligned)
static constexpr int NT  = Ktot / BK;  // 16 K-steps

// out[b,s,h,a] = sum_f value_input[b,s,f] * v_w[h,f,a]
// (reference softmax over q integrates to exactly 1 in the final q-contraction,
//  so the whole op reduces to the value-projection GEMM)
// A = value_input [M=4096][K=1024] row-major fp32
// W = v_w [H=16][K=1024][64] ; n = h*64+a ; BN=128 spans exactly 2 heads
// C = out [M][N=1024] row-major fp32
__global__ __launch_bounds__(512, 2)
void vproj_gemm_kernel(const float* __restrict__ A,
                       const float* __restrict__ W,
                       float* __restrict__ C)
{
    __shared__ bf16_t As[2][BM][BKP];   // double-buffered
    __shared__ bf16_t Bs[2][BN][BKP];   // transposed: [n][k]

    const int t    = threadIdx.x;
    const int lane = t & 63;
    const int wave = t >> 6;     // 0..7
    const int wm   = wave >> 2;  // 0..1  (64-row halves)
    const int wn   = wave & 3;   // 0..3  (32-col quarters)

    // XCD-aware swizzle: 256 wgs, 8 XCDs -> XCD j owns 32 consecutive tiles
    // (4 M-panels x all 8 N-tiles): A slice 2.1 MB + W 4.2 MB ~ L2-resident.
    const int tile = (blockIdx.x & 7) * 32 + (blockIdx.x >> 3);
    const int bx = tile & 7;     // N-tile 0..7
    const int by = tile >> 3;    // M-tile 0..31
    const int bm = by * BM;
    const int bn = bx * BN;

    // ---- staging coordinates ----
    // A: 4 x float4 per thread; idx = r*512+t -> row = idx>>4, c4 = idx&15
    // B: one 4k x 4a micro-tile per thread
    const int bhead = t >> 8;        // 0..1 (which head within the 2-head slab)
    const int brem  = t & 255;
    const int bkq   = brem >> 4;     // 0..15 : k-quad
    const int baq   = brem & 15;     // 0..15 : a-quad
    const float* const wbase = W + ((size_t)((bn >> 6) + bhead)) * (Ktot * 64)
                                 + (size_t)(bkq * 4) * 64 + baq * 4;

    f32x4 avreg[4], bvreg[4];

    auto load_tile = [&](int k0) {
#pragma unroll
        for (int r = 0; r < 4; ++r) {
            const int idx = r * 512 + t;
            const int row = idx >> 4, c4 = idx & 15;
            avreg[r] = *(const f32x4*)(A + (size_t)(bm + row) * Ktot + k0 + c4 * 4);
        }
        const float* wp = wbase + (size_t)k0 * 64;
#pragma unroll
        for (int r = 0; r < 4; ++r)
            bvreg[r] = *(const f32x4*)(wp + r * 64);
    };

    auto store_tile = [&](int buf) {
#pragma unroll
        for (int r = 0; r < 4; ++r) {
            const int idx = r * 512 + t;
            const int row = idx >> 4, c4 = idx & 15;
            bf16x4 p = {(bf16_t)avreg[r].x, (bf16_t)avreg[r].y,
                        (bf16_t)avreg[r].z, (bf16_t)avreg[r].w};
            *(bf16x4*)&As[buf][row][c4 * 4] = p;
        }
        // 4x4 in-register transpose: global [k][a] -> LDS [a][k]
#pragma unroll
        for (int j = 0; j < 4; ++j) {
            bf16x4 p = {(bf16_t)bvreg[0][j], (bf16_t)bvreg[1][j],
                        (bf16_t)bvreg[2][j], (bf16_t)bvreg[3][j]};
            *(bf16x4*)&Bs[buf][bhead * 64 + baq * 4 + j][bkq * 4] = p;
        }
    };

    f32x4 acc[4][2];
#pragma unroll
    for (int mf = 0; mf < 4; ++mf)
#pragma unroll
        for (int nf = 0; nf < 2; ++nf) {
            f32x4 z = {0.f, 0.f, 0.f, 0.f};
            acc[mf][nf] = z;
        }

    const int lrow = lane & 15;
    const int lkb  = (lane >> 4) << 3;   // 8-elem k-group within a 32-chunk

    // prologue: stage tile 0
    load_tile(0);
    store_tile(0);
    __syncthreads();

    for (int tI = 0; tI < NT; ++tI) {
        const int cur = tI & 1;

        // issue next tile's global loads early (latency hides under MFMA)
        if (tI + 1 < NT) load_tile((tI + 1) * BK);

        // compute current tile
#pragma unroll
        for (int kk = 0; kk < 2; ++kk) {
            bf16x8 af[4], bfr[2];
#pragma unroll
            for (int mf = 0; mf < 4; ++mf)
                af[mf] = *(const bf16x8*)&As[cur][wm * 64 + mf * 16 + lrow][kk * 32 + lkb];
#pragma unroll
            for (int nf = 0; nf < 2; ++nf)
                bfr[nf] = *(const bf16x8*)&Bs[cur][wn * 32 + nf * 16 + lrow][kk * 32 + lkb];
#pragma unroll
            for (int mf = 0; mf < 4; ++mf)
#pragma unroll
                for (int nf = 0; nf < 2; ++nf)
                    acc[mf][nf] = __builtin_amdgcn_mfma_f32_16x16x32_bf16(
                        af[mf], bfr[nf], acc[mf][nf], 0, 0, 0);
        }

        // convert + write next tile into the other buffer
        if (tI + 1 < NT) store_tile(cur ^ 1);

        __syncthreads();
    }

    // ---- epilogue: C/D layout col = lane&15, row = (lane>>4)*4 + i ----
#pragma unroll
    for (int mf = 0; mf < 4; ++mf) {
        const int row0 = bm + wm * 64 + mf * 16 + ((lane >> 4) << 2);
#pragma unroll
        for (int nf = 0; nf < 2; ++nf) {
            const int col = bn + wn * 32 + nf * 16 + (lane & 15);
#pragma unroll
            for (int i = 0; i < 4; ++i)
                C[(size_t)(row0 + i) * Ntot + col] = acc[mf][nf][i];
        }
    }
}

extern "C" void kernel_launch(void* const* d_in, const int* in_sizes, int n_in,
                              void* d_out, int out_size, void* d_ws, size_t ws_size,
                              hipStream_t stream) {
    (void)in_sizes; (void)n_in; (void)d_ws; (void)ws_size; (void)out_size;
    // setup_inputs order: key_input, query_input, value_input, q_w, k_w, v_w
    const float* V  = (const float*)d_in[2];   // [B,S,F] = [M][K]
    const float* Vw = (const float*)d_in[5];   // [H,F,A]
    float* out      = (float*)d_out;           // [B,S,H,A] = [M][N]

    const int nwg = (Mtot / BM) * (Ntot / BN); // 32 * 8 = 256
    hipLaunchKernelGGL(vproj_gemm_kernel, dim3(nwg), dim3(512), 0, stream, V, Vw, out);
}

// Round 3
// 32.620 us; speedup vs baseline: 1.4066x; 1.0168x over previous
//
#include <hip/hip_runtime.h>
#include <hip/hip_bf16.h>

typedef __bf16 bf16_t;
typedef __bf16 bf16x4 __attribute__((ext_vector_type(4)));
typedef __bf16 bf16x8 __attribute__((ext_vector_type(8)));
typedef float  f32x4  __attribute__((ext_vector_type(4)));

typedef __attribute__((address_space(1))) const void  gvoid_t;
typedef __attribute__((address_space(3))) void        lvoid_t;

static constexpr int Mtot = 4096;   // B*S
static constexpr int Ntot = 1024;   // H*A
static constexpr int Ktot = 1024;   // F

// out[b,s,h,a] = sum_f value_input[b,s,f] * v_w[h,f,a]
// (reference softmax over q integrates to exactly 1 in the final q-contraction)

// ============================================================================
// Prepass: Ab = bf16(A) [4096][1024]; Wt = bf16 transpose of W: [n=h*64+a][k]
// ============================================================================
__global__ __launch_bounds__(256)
void prepass_kernel(const float* __restrict__ A, const float* __restrict__ W,
                    bf16_t* __restrict__ Ab, bf16_t* __restrict__ Wt)
{
    __shared__ float wtile[64][65];   // padded fp32 transpose tile
    const int bid = blockIdx.x, t = threadIdx.x;

    if (bid < 1024) {
        // A convert: 4096 floats per block, fully coalesced
        const size_t base = (size_t)bid * 4096 + t * 4;
#pragma unroll
        for (int r = 0; r < 4; ++r) {
            const size_t i = base + (size_t)r * 1024;
            const f32x4 v = *(const f32x4*)(A + i);
            bf16x4 p = {(bf16_t)v[0], (bf16_t)v[1], (bf16_t)v[2], (bf16_t)v[3]};
            *(bf16x4*)(Ab + i) = p;
        }
    } else {
        // W transpose: block handles one head x one 64k-slab
        const int wb = bid - 1024;        // 0..255
        const int head = wb >> 4;         // 0..15
        const int k0 = (wb & 15) * 64;
        const float* wsrc = W + (size_t)head * (Ktot * 64) + (size_t)k0 * 64;
        // load [64k][64a] coalesced
#pragma unroll
        for (int i = 0; i < 4; ++i) {
            const int idx = i * 256 + t;
            const int kr = idx >> 4, a4 = (idx & 15) * 4;
            const f32x4 v = *(const f32x4*)(wsrc + (size_t)kr * 64 + a4);
            wtile[kr][a4 + 0] = v[0]; wtile[kr][a4 + 1] = v[1];
            wtile[kr][a4 + 2] = v[2]; wtile[kr][a4 + 3] = v[3];
        }
        __syncthreads();
        // store transposed [64a][64k] as bf16, coalesced
#pragma unroll
        for (int i = 0; i < 4; ++i) {
            const int idx = i * 256 + t;
            const int ar = idx >> 4, kc = (idx & 15) * 4;
            bf16x4 p = {(bf16_t)wtile[kc + 0][ar], (bf16_t)wtile[kc + 1][ar],
                        (bf16_t)wtile[kc + 2][ar], (bf16_t)wtile[kc + 3][ar]};
            *(bf16x4*)(Wt + (size_t)(head * 64 + ar) * Ktot + k0 + kc) = p;
        }
    }
}

// ============================================================================
// GEMM: C[4096][1024] f32 = Ab[4096][1024] x Wt^T ; both operands k-contiguous
// BM=64 BN=128 BK=64, 4 waves (2x2, wave-tile 32x64), grid 512 = 2 blocks/CU
// T3 minimum 2-phase: STAGE(next) -> compute(cur) -> barrier
// ============================================================================
__global__ __launch_bounds__(256, 2)
void gemm_bf16_kernel(const bf16_t* __restrict__ Ab, const bf16_t* __restrict__ Bt,
                      float* __restrict__ C)
{
    __shared__ bf16_t As[2][64 * 64];    // linear [row][64k]
    __shared__ bf16_t Bs[2][128 * 64];   // linear [col][64k]

    const int t = threadIdx.x, lane = t & 63, wave = t >> 6;
    const int wm = wave & 1, wn = wave >> 1;

    // XCD swizzle: 512 wgs, XCD x owns g in [x*64, x*64+64) = 8 M-panels x 8 N
    // per-XCD footprint: A 1 MB + W 2.1 MB < 4 MB L2
    const int g = (blockIdx.x & 7) * 64 + (blockIdx.x >> 3);
    const int by = g >> 3, bx = g & 7;
    const int bm = by * 64, bn = bx * 128;

    const int lrow = lane & 15;
    const int lkb = (lane >> 4) * 8;

    f32x4 acc[2][4];
#pragma unroll
    for (int mf = 0; mf < 2; ++mf)
#pragma unroll
        for (int nf = 0; nf < 4; ++nf) {
            f32x4 z = {0.f, 0.f, 0.f, 0.f};
            acc[mf][nf] = z;
        }

    auto STAGE = [&](int buf, int k0) {
        // A tile: 64 rows x 64 k bf16 = 512 x 16B chunks; 2 per thread
#pragma unroll
        for (int j = 0; j < 2; ++j) {
            const int chunk = (wave * 2 + j) * 64 + lane;   // 0..511
            const int row = chunk >> 3, kb = (chunk & 7) * 8;
            const bf16_t* gp = Ab + (size_t)(bm + row) * Ktot + k0 + kb;
            __builtin_amdgcn_global_load_lds((gvoid_t*)gp,
                (lvoid_t*)&As[buf][(wave * 2 + j) * 512], 16, 0, 0);
        }
        // B tile: 128 rows x 64 k = 1024 chunks; 4 per thread
#pragma unroll
        for (int j = 0; j < 4; ++j) {
            const int chunk = (wave * 4 + j) * 64 + lane;   // 0..1023
            const int row = chunk >> 3, kb = (chunk & 7) * 8;
            const bf16_t* gp = Bt + (size_t)(bn + row) * Ktot + k0 + kb;
            __builtin_amdgcn_global_load_lds((gvoid_t*)gp,
                (lvoid_t*)&Bs[buf][(wave * 4 + j) * 512], 16, 0, 0);
        }
    };

    STAGE(0, 0);
    __syncthreads();   // compiler emits vmcnt(0) drain before barrier

    constexpr int NT = Ktot / 64;   // 16
    for (int tI = 0; tI < NT; ++tI) {
        const int cur = tI & 1;
        if (tI + 1 < NT) STAGE(cur ^ 1, (tI + 1) * 64);

#pragma unroll
        for (int kk = 0; kk < 2; ++kk) {
            bf16x8 af[2], bfr[4];
#pragma unroll
            for (int mf = 0; mf < 2; ++mf)
                af[mf] = *(const bf16x8*)&As[cur][(wm * 32 + mf * 16 + lrow) * 64 + kk * 32 + lkb];
#pragma unroll
            for (int nf = 0; nf < 4; ++nf)
                bfr[nf] = *(const bf16x8*)&Bs[cur][(wn * 64 + nf * 16 + lrow) * 64 + kk * 32 + lkb];
            __builtin_amdgcn_s_setprio(1);
#pragma unroll
            for (int mf = 0; mf < 2; ++mf)
#pragma unroll
                for (int nf = 0; nf < 4; ++nf)
                    acc[mf][nf] = __builtin_amdgcn_mfma_f32_16x16x32_bf16(
                        af[mf], bfr[nf], acc[mf][nf], 0, 0, 0);
            __builtin_amdgcn_s_setprio(0);
        }
        __syncthreads();   // drains vmcnt (next tile staged) + lgkm
    }

    // epilogue: C/D layout col = lane&15, row = (lane>>4)*4 + i
#pragma unroll
    for (int mf = 0; mf < 2; ++mf) {
        const int row0 = bm + wm * 32 + mf * 16 + ((lane >> 4) << 2);
#pragma unroll
        for (int nf = 0; nf < 4; ++nf) {
            const int col = bn + wn * 64 + nf * 16 + (lane & 15);
#pragma unroll
            for (int i = 0; i < 4; ++i)
                C[(size_t)(row0 + i) * Ntot + col] = acc[mf][nf][i];
        }
    }
}

// ============================================================================
// Fallback (ws too small): round-2 fused kernel, proven correct at 33 us
// ============================================================================
static constexpr int FBM = 128, FBN = 128, FBK = 64, FBKP = 72;

__global__ __launch_bounds__(512, 2)
void vproj_fused_kernel(const float* __restrict__ A, const float* __restrict__ W,
                        float* __restrict__ C)
{
    __shared__ bf16_t As[2][FBM][FBKP];
    __shared__ bf16_t Bs[2][FBN][FBKP];

    const int t = threadIdx.x, lane = t & 63, wave = t >> 6;
    const int wm = wave >> 2, wn = wave & 3;
    const int tile = (blockIdx.x & 7) * 32 + (blockIdx.x >> 3);
    const int bm = (tile >> 3) * FBM, bn = (tile & 7) * FBN;

    const int bhead = t >> 8, brem = t & 255;
    const int bkq = brem >> 4, baq = brem & 15;
    const float* const wbase = W + ((size_t)((bn >> 6) + bhead)) * (Ktot * 64)
                                 + (size_t)(bkq * 4) * 64 + baq * 4;
    f32x4 avreg[4], bvreg[4];

    auto load_tile = [&](int k0) {
#pragma unroll
        for (int r = 0; r < 4; ++r) {
            const int idx = r * 512 + t;
            avreg[r] = *(const f32x4*)(A + (size_t)(bm + (idx >> 4)) * Ktot + k0 + (idx & 15) * 4);
        }
        const float* wp = wbase + (size_t)k0 * 64;
#pragma unroll
        for (int r = 0; r < 4; ++r) bvreg[r] = *(const f32x4*)(wp + r * 64);
    };
    auto store_tile = [&](int buf) {
#pragma unroll
        for (int r = 0; r < 4; ++r) {
            const int idx = r * 512 + t;
            bf16x4 p = {(bf16_t)avreg[r][0], (bf16_t)avreg[r][1],
                        (bf16_t)avreg[r][2], (bf16_t)avreg[r][3]};
            *(bf16x4*)&As[buf][idx >> 4][(idx & 15) * 4] = p;
        }
#pragma unroll
        for (int j = 0; j < 4; ++j) {
            bf16x4 p = {(bf16_t)bvreg[0][j], (bf16_t)bvreg[1][j],
                        (bf16_t)bvreg[2][j], (bf16_t)bvreg[3][j]};
            *(bf16x4*)&Bs[buf][bhead * 64 + baq * 4 + j][bkq * 4] = p;
        }
    };

    f32x4 acc[4][2];
#pragma unroll
    for (int mf = 0; mf < 4; ++mf)
#pragma unroll
        for (int nf = 0; nf < 2; ++nf) { f32x4 z = {0,0,0,0}; acc[mf][nf] = z; }

    const int lrow = lane & 15, lkb = (lane >> 4) << 3;
    load_tile(0); store_tile(0); __syncthreads();

    for (int tI = 0; tI < Ktot / FBK; ++tI) {
        const int cur = tI & 1;
        if (tI + 1 < Ktot / FBK) load_tile((tI + 1) * FBK);
#pragma unroll
        for (int kk = 0; kk < 2; ++kk) {
            bf16x8 af[4], bfr[2];
#pragma unroll
            for (int mf = 0; mf < 4; ++mf)
                af[mf] = *(const bf16x8*)&As[cur][wm * 64 + mf * 16 + lrow][kk * 32 + lkb];
#pragma unroll
            for (int nf = 0; nf < 2; ++nf)
                bfr[nf] = *(const bf16x8*)&Bs[cur][wn * 32 + nf * 16 + lrow][kk * 32 + lkb];
#pragma unroll
            for (int mf = 0; mf < 4; ++mf)
#pragma unroll
                for (int nf = 0; nf < 2; ++nf)
                    acc[mf][nf] = __builtin_amdgcn_mfma_f32_16x16x32_bf16(
                        af[mf], bfr[nf], acc[mf][nf], 0, 0, 0);
        }
        if (tI + 1 < Ktot / FBK) store_tile(cur ^ 1);
        __syncthreads();
    }
#pragma unroll
    for (int mf = 0; mf < 4; ++mf) {
        const int row0 = bm + wm * 64 + mf * 16 + ((lane >> 4) << 2);
#pragma unroll
        for (int nf = 0; nf < 2; ++nf) {
            const int col = bn + wn * 32 + nf * 16 + (lane & 15);
#pragma unroll
            for (int i = 0; i < 4; ++i)
                C[(size_t)(row0 + i) * Ntot + col] = acc[mf][nf][i];
        }
    }
}

extern "C" void kernel_launch(void* const* d_in, const int* in_sizes, int n_in,
                              void* d_out, int out_size, void* d_ws, size_t ws_size,
                              hipStream_t stream) {
    (void)in_sizes; (void)n_in; (void)out_size;
    const float* V  = (const float*)d_in[2];   // [B,S,F] = [M][K]
    const float* Vw = (const float*)d_in[5];   // [H,F,A]
    float* out      = (float*)d_out;           // [B,S,H,A] = [M][N]

    const size_t abBytes = (size_t)Mtot * Ktot * sizeof(bf16_t);   // 8 MiB
    const size_t wtBytes = (size_t)Ntot * Ktot * sizeof(bf16_t);   // 2 MiB

    if (ws_size >= abBytes + wtBytes) {
        bf16_t* Ab = (bf16_t*)d_ws;
        bf16_t* Wt = (bf16_t*)((char*)d_ws + abBytes);
        hipLaunchKernelGGL(prepass_kernel, dim3(1024 + 256), dim3(256), 0, stream,
                           V, Vw, Ab, Wt);
        hipLaunchKernelGGL(gemm_bf16_kernel, dim3((Mtot / 64) * (Ntot / 128)),
                           dim3(256), 0, stream, Ab, Wt, out);
    } else {
        hipLaunchKernelGGL(vproj_fused_kernel, dim3(256), dim3(512), 0, stream,
                           V, Vw, out);
    }
}

// Round 4
// 28.309 us; speedup vs baseline: 1.6209x; 1.1523x over previous
//
#include <hip/hip_runtime.h>
#include <hip/hip_bf16.h>

typedef __bf16 bf16_t;
typedef __bf16 bf16x4 __attribute__((ext_vector_type(4)));
typedef __bf16 bf16x8 __attribute__((ext_vector_type(8)));
typedef float  f32x4  __attribute__((ext_vector_type(4)));

typedef __attribute__((address_space(1))) const void  gvoid_t;
typedef __attribute__((address_space(3))) void        lvoid_t;

static constexpr int Mtot = 4096;   // B*S
static constexpr int Ntot = 1024;   // H*A
static constexpr int Ktot = 1024;   // F

// out[b,s,h,a] = sum_f value_input[b,s,f] * v_w[h,f,a]
// (reference softmax over q integrates to exactly 1 in the final q-contraction)

// ============================================================================
// Prepass: Ab = bf16(A) [4096][1024]; Wt = bf16 transpose of W: [n=h*64+a][k]
// ============================================================================
__global__ __launch_bounds__(256)
void prepass_kernel(const float* __restrict__ A, const float* __restrict__ W,
                    bf16_t* __restrict__ Ab, bf16_t* __restrict__ Wt)
{
    __shared__ float wtile[64][65];   // padded fp32 transpose tile
    const int bid = blockIdx.x, t = threadIdx.x;

    if (bid < 1024) {
        const size_t base = (size_t)bid * 4096 + t * 4;
#pragma unroll
        for (int r = 0; r < 4; ++r) {
            const size_t i = base + (size_t)r * 1024;
            const f32x4 v = *(const f32x4*)(A + i);
            bf16x4 p = {(bf16_t)v[0], (bf16_t)v[1], (bf16_t)v[2], (bf16_t)v[3]};
            *(bf16x4*)(Ab + i) = p;
        }
    } else {
        const int wb = bid - 1024;        // 0..255
        const int head = wb >> 4;         // 0..15
        const int k0 = (wb & 15) * 64;
        const float* wsrc = W + (size_t)head * (Ktot * 64) + (size_t)k0 * 64;
#pragma unroll
        for (int i = 0; i < 4; ++i) {
            const int idx = i * 256 + t;
            const int kr = idx >> 4, a4 = (idx & 15) * 4;
            const f32x4 v = *(const f32x4*)(wsrc + (size_t)kr * 64 + a4);
            wtile[kr][a4 + 0] = v[0]; wtile[kr][a4 + 1] = v[1];
            wtile[kr][a4 + 2] = v[2]; wtile[kr][a4 + 3] = v[3];
        }
        __syncthreads();
#pragma unroll
        for (int i = 0; i < 4; ++i) {
            const int idx = i * 256 + t;
            const int ar = idx >> 4, kc = (idx & 15) * 4;
            bf16x4 p = {(bf16_t)wtile[kc + 0][ar], (bf16_t)wtile[kc + 1][ar],
                        (bf16_t)wtile[kc + 2][ar], (bf16_t)wtile[kc + 3][ar]};
            *(bf16x4*)(Wt + (size_t)(head * 64 + ar) * Ktot + k0 + kc) = p;
        }
    }
}

// ============================================================================
// GEMM: C[4096][1024] f32 = Ab x Wt^T, both operands [row][k] k-contiguous.
// BM=64 BN=128 BK=64, 4 waves (2x2), grid 512 = 2 blocks/CU.
// T2 XOR-swizzle (rule #21 form): LDS dest linear, global SOURCE pre-permuted
// within each row's 128B window (chunk&7 ^ row&7), ds_read applies same XOR.
// => fragment ds_read_b128: each 8-lane group covers all 32 banks, conflict-free.
// ============================================================================
__global__ __launch_bounds__(256, 2)
void gemm_bf16_kernel(const bf16_t* __restrict__ Ab, const bf16_t* __restrict__ Bt,
                      float* __restrict__ C)
{
    __shared__ bf16_t As[2][64 * 64];    // [row][64k], rows 128B, swizzled content
    __shared__ bf16_t Bs[2][128 * 64];

    const int t = threadIdx.x, lane = t & 63, wave = t >> 6;
    const int wm = wave & 1, wn = wave >> 1;

    // XCD swizzle: 512 wgs; XCD x owns 8 M-panels x all 8 N => A 1MB + W 2.1MB < 4MB L2
    const int g = (blockIdx.x & 7) * 64 + (blockIdx.x >> 3);
    const int by = g >> 3, bx = g & 7;
    const int bm = by * 64, bn = bx * 128;

    const int lrow = lane & 15;
    const int lq   = lane >> 4;          // quarter-wave 0..3

    f32x4 acc[2][4];
#pragma unroll
    for (int mf = 0; mf < 2; ++mf)
#pragma unroll
        for (int nf = 0; nf < 4; ++nf) {
            f32x4 z = {0.f, 0.f, 0.f, 0.f};
            acc[mf][nf] = z;
        }

    auto STAGE = [&](int buf, int k0) {
        // A: 64x64 bf16 = 512 16B-chunks, 2/thread. Source col permuted by row.
#pragma unroll
        for (int j = 0; j < 2; ++j) {
            const int chunk = (wave * 2 + j) * 64 + lane;
            const int row = chunk >> 3;
            const int kb  = ((chunk & 7) ^ (row & 7)) * 8;   // swizzled source col
            const bf16_t* gp = Ab + (size_t)(bm + row) * Ktot + k0 + kb;
            __builtin_amdgcn_global_load_lds((gvoid_t*)gp,
                (lvoid_t*)&As[buf][(wave * 2 + j) * 512], 16, 0, 0);
        }
        // B: 128x64 = 1024 chunks, 4/thread
#pragma unroll
        for (int j = 0; j < 4; ++j) {
            const int chunk = (wave * 4 + j) * 64 + lane;
            const int row = chunk >> 3;
            const int kb  = ((chunk & 7) ^ (row & 7)) * 8;
            const bf16_t* gp = Bt + (size_t)(bn + row) * Ktot + k0 + kb;
            __builtin_amdgcn_global_load_lds((gvoid_t*)gp,
                (lvoid_t*)&Bs[buf][(wave * 4 + j) * 512], 16, 0, 0);
        }
    };

    STAGE(0, 0);
    __syncthreads();

    constexpr int NT = Ktot / 64;   // 16
    for (int tI = 0; tI < NT; ++tI) {
        const int cur = tI & 1;
        if (tI + 1 < NT) STAGE(cur ^ 1, (tI + 1) * 64);

#pragma unroll
        for (int kk = 0; kk < 2; ++kk) {
            const int c16 = kk * 4 + lq;          // 16B-column 0..7
            bf16x8 af[2], bfr[4];
#pragma unroll
            for (int mf = 0; mf < 2; ++mf) {
                const int R = wm * 32 + mf * 16 + lrow;
                af[mf] = *(const bf16x8*)&As[cur][R * 64 + (c16 ^ (R & 7)) * 8];
            }
#pragma unroll
            for (int nf = 0; nf < 4; ++nf) {
                const int R = wn * 64 + nf * 16 + lrow;
                bfr[nf] = *(const bf16x8*)&Bs[cur][R * 64 + (c16 ^ (R & 7)) * 8];
            }
            __builtin_amdgcn_s_setprio(1);
#pragma unroll
            for (int mf = 0; mf < 2; ++mf)
#pragma unroll
                for (int nf = 0; nf < 4; ++nf)
                    acc[mf][nf] = __builtin_amdgcn_mfma_f32_16x16x32_bf16(
                        af[mf], bfr[nf], acc[mf][nf], 0, 0, 0);
            __builtin_amdgcn_s_setprio(0);
        }
        __syncthreads();
    }

    // epilogue: C/D layout col = lane&15, row = (lane>>4)*4 + i
#pragma unroll
    for (int mf = 0; mf < 2; ++mf) {
        const int row0 = bm + wm * 32 + mf * 16 + (lq << 2);
#pragma unroll
        for (int nf = 0; nf < 4; ++nf) {
            const int col = bn + wn * 64 + nf * 16 + lrow;
#pragma unroll
            for (int i = 0; i < 4; ++i)
                C[(size_t)(row0 + i) * Ntot + col] = acc[mf][nf][i];
        }
    }
}

// ============================================================================
// Fallback (ws too small): round-2 fused kernel (proven correct, ~33 us)
// ============================================================================
static constexpr int FBM = 128, FBN = 128, FBK = 64, FBKP = 72;

__global__ __launch_bounds__(512, 2)
void vproj_fused_kernel(const float* __restrict__ A, const float* __restrict__ W,
                        float* __restrict__ C)
{
    __shared__ bf16_t As[2][FBM][FBKP];
    __shared__ bf16_t Bs[2][FBN][FBKP];

    const int t = threadIdx.x, lane = t & 63, wave = t >> 6;
    const int wm = wave >> 2, wn = wave & 3;
    const int tile = (blockIdx.x & 7) * 32 + (blockIdx.x >> 3);
    const int bm = (tile >> 3) * FBM, bn = (tile & 7) * FBN;

    const int bhead = t >> 8, brem = t & 255;
    const int bkq = brem >> 4, baq = brem & 15;
    const float* const wbase = W + ((size_t)((bn >> 6) + bhead)) * (Ktot * 64)
                                 + (size_t)(bkq * 4) * 64 + baq * 4;
    f32x4 avreg[4], bvreg[4];

    auto load_tile = [&](int k0) {
#pragma unroll
        for (int r = 0; r < 4; ++r) {
            const int idx = r * 512 + t;
            avreg[r] = *(const f32x4*)(A + (size_t)(bm + (idx >> 4)) * Ktot + k0 + (idx & 15) * 4);
        }
        const float* wp = wbase + (size_t)k0 * 64;
#pragma unroll
        for (int r = 0; r < 4; ++r) bvreg[r] = *(const f32x4*)(wp + r * 64);
    };
    auto store_tile = [&](int buf) {
#pragma unroll
        for (int r = 0; r < 4; ++r) {
            const int idx = r * 512 + t;
            bf16x4 p = {(bf16_t)avreg[r][0], (bf16_t)avreg[r][1],
                        (bf16_t)avreg[r][2], (bf16_t)avreg[r][3]};
            *(bf16x4*)&As[buf][idx >> 4][(idx & 15) * 4] = p;
        }
#pragma unroll
        for (int j = 0; j < 4; ++j) {
            bf16x4 p = {(bf16_t)bvreg[0][j], (bf16_t)bvreg[1][j],
                        (bf16_t)bvreg[2][j], (bf16_t)bvreg[3][j]};
            *(bf16x4*)&Bs[buf][bhead * 64 + baq * 4 + j][bkq * 4] = p;
        }
    };

    f32x4 acc[4][2];
#pragma unroll
    for (int mf = 0; mf < 4; ++mf)
#pragma unroll
        for (int nf = 0; nf < 2; ++nf) { f32x4 z = {0,0,0,0}; acc[mf][nf] = z; }

    const int lrow = lane & 15, lkb = (lane >> 4) << 3;
    load_tile(0); store_tile(0); __syncthreads();

    for (int tI = 0; tI < Ktot / FBK; ++tI) {
        const int cur = tI & 1;
        if (tI + 1 < Ktot / FBK) load_tile((tI + 1) * FBK);
#pragma unroll
        for (int kk = 0; kk < 2; ++kk) {
            bf16x8 af[4], bfr[2];
#pragma unroll
            for (int mf = 0; mf < 4; ++mf)
                af[mf] = *(const bf16x8*)&As[cur][wm * 64 + mf * 16 + lrow][kk * 32 + lkb];
#pragma unroll
            for (int nf = 0; nf < 2; ++nf)
                bfr[nf] = *(const bf16x8*)&Bs[cur][wn * 32 + nf * 16 + lrow][kk * 32 + lkb];
#pragma unroll
            for (int mf = 0; mf < 4; ++mf)
#pragma unroll
                for (int nf = 0; nf < 2; ++nf)
                    acc[mf][nf] = __builtin_amdgcn_mfma_f32_16x16x32_bf16(
                        af[mf], bfr[nf], acc[mf][nf], 0, 0, 0);
        }
        if (tI + 1 < Ktot / FBK) store_tile(cur ^ 1);
        __syncthreads();
    }
#pragma unroll
    for (int mf = 0; mf < 4; ++mf) {
        const int row0 = bm + wm * 64 + mf * 16 + ((lane >> 4) << 2);
#pragma unroll
        for (int nf = 0; nf < 2; ++nf) {
            const int col = bn + wn * 32 + nf * 16 + (lane & 15);
#pragma unroll
            for (int i = 0; i < 4; ++i)
                C[(size_t)(row0 + i) * Ntot + col] = acc[mf][nf][i];
        }
    }
}

extern "C" void kernel_launch(void* const* d_in, const int* in_sizes, int n_in,
                              void* d_out, int out_size, void* d_ws, size_t ws_size,
                              hipStream_t stream) {
    (void)in_sizes; (void)n_in; (void)out_size;
    const float* V  = (const float*)d_in[2];   // [B,S,F] = [M][K]
    const float* Vw = (const float*)d_in[5];   // [H,F,A]
    float* out      = (float*)d_out;           // [B,S,H,A] = [M][N]

    const size_t abBytes = (size_t)Mtot * Ktot * sizeof(bf16_t);   // 8 MiB
    const size_t wtBytes = (size_t)Ntot * Ktot * sizeof(bf16_t);   // 2 MiB

    if (ws_size >= abBytes + wtBytes) {
        bf16_t* Ab = (bf16_t*)d_ws;
        bf16_t* Wt = (bf16_t*)((char*)d_ws + abBytes);
        hipLaunchKernelGGL(prepass_kernel, dim3(1024 + 256), dim3(256), 0, stream,
                           V, Vw, Ab, Wt);
        hipLaunchKernelGGL(gemm_bf16_kernel, dim3((Mtot / 64) * (Ntot / 128)),
                           dim3(256), 0, stream, Ab, Wt, out);
    } else {
        hipLaunchKernelGGL(vproj_fused_kernel, dim3(256), dim3(512), 0, stream,
                           V, Vw, out);
    }
}